// Round 18
// baseline (14.128 us; speedup 1.0000x reference)
//
#include <hip/hip_runtime.h>

// MFMA aspect-grouped 2-layer MLP, 2 dispatches, in-LDS transpose.
//   gemm1:  flat 640-block grid: hs=bid/80 (0..7, 32-col slice), p=bid%80,
//           aid=p%20, dk=p/20 (0..3, 192-k slice). hs stride 80 = 0 mod 8 ->
//           the 8 hs-blocks sharing one (aid,dk) X-slice sit on one XCD.
//           Wave 0 ballot-scans aspect_ids (int4, deterministic, identical in
//           every block) -> sidx (padded to x64) while waves 1-3 transpose
//           W1 tile [192k][32c] fp32 -> bf16 W1T_lds [32c][192k] via 4k x 4c
//           subtiles (uint2 writes); one barrier. One X stage [64][192] bf16
//           at b128 (8 floats/iter). Wave role: ct=w&1 col-tile, sh=w>>1
//           sample-half: 32 samples x 16 cols x 192k = 12 MFMA (6 B + 12 A
//           ds_read_b128). bf16 part INTERLEAVED [sample][colOct][dk][8]
//           (+b1 folded at dk==0) so finish reads one 64B line per thread.
//   finish: 128 blocks; 2 samples/wave (32 lanes x 8 cols); the 4 dk-
//           fragments per thread are 4 CONTIGUOUS uint4 (one cache line);
//           ReLU, x W2 + b2 -> out.

constexpr int D  = 768;
constexpr int H  = 256;
constexpr int NA = 20;
constexpr int NB = 1024;
constexpr int S  = 64;            // samples per chunk (aspects avg ~51 -> 1 chunk)
constexpr int DKN = 4;            // d-slices
constexpr int KS  = D / DKN;      // 192 k per block
constexpr int HSN = 8;            // 32-col slices
constexpr int RW  = KS + 8;       // 200 shorts/row (400B, 16B-aligned)

constexpr size_t WS_NEEDED = (size_t)NB * DKN * H * 2;   // bf16 part: 2 MB

typedef __attribute__((ext_vector_type(8))) short short8v;  // 8 bf16
typedef __attribute__((ext_vector_type(4))) float f32x4;

__device__ __forceinline__ unsigned f2bf(float x) {   // RTN-even, low 16
    const unsigned u = __float_as_uint(x);
    return (u + 0x7FFFu + ((u >> 16) & 1u)) >> 16;
}
__device__ __forceinline__ float bflo(unsigned u) { return __uint_as_float(u << 16); }
__device__ __forceinline__ float bfhi(unsigned u) { return __uint_as_float(u & 0xFFFF0000u); }

__global__ __launch_bounds__(256, 3) void gemm1_kernel(
    const float* __restrict__ X,
    const int*   __restrict__ aids,
    const float* __restrict__ W1,
    const float* __restrict__ b1,
    unsigned short* __restrict__ part)   // bf16 [NB][32 colOct][DKN][8]
{
    __shared__ __align__(16) short w1t[32 * RW];   // bf16 W1T [32c][192k]
    __shared__ __align__(16) short xl[S * RW];     // bf16 X   [64s][192k]
    __shared__ int sidx[NB + S];
    __shared__ int n_sh;

    const int t = threadIdx.x;
    const int w = t >> 6, l = t & 63;
    const int bid = blockIdx.x;
    const int hs  = bid / 80;          // 0..7, 32-col slice
    const int p   = bid - hs * 80;     // 0..79
    const int aid = p % NA;            // 0..19
    const int dk  = p / NA;            // 0..3, 192-k slice

    if (w == 0) {
        // wave 0: ballot-scan, int4 loads; deterministic interleaved order,
        // identical in every block.
        int run = 0;
        #pragma unroll
        for (int base = 0; base < NB; base += 256) {
            const int4 v = *reinterpret_cast<const int4*>(&aids[base + l * 4]);
            #pragma unroll
            for (int j = 0; j < 4; ++j) {
                const int id = (j == 0) ? v.x : (j == 1) ? v.y : (j == 2) ? v.z : v.w;
                const unsigned long long m = __ballot(id == aid);
                const int pre = run + __popcll(m & ((1ull << l) - 1));
                if (id == aid) sidx[pre] = base + l * 4 + j;
                run += __popcll(m);
            }
        }
        if (run > 0) {
            const int last = sidx[run - 1];          // own-wave write, ordered
            const int npad = ((run + S - 1) / S) * S;
            if (run + l < npad) sidx[run + l] = last;
        }
        if (l == 0) n_sh = run;
    } else {
        // waves 1-3: W1 tile [192k][32c] -> bf16 W1T_lds [32c][192k].
        // i -> (k-quad kq4 0..47, col-quad cq 0..7): 4 f4 loads (rows
        // 4kq4..+3, cols cq*4..+3), pack 4 k per col -> uint2 write.
        const float* W1s = W1 + (size_t)aid * D * H + (size_t)dk * KS * H + hs * 32;
        uint2* w1v = reinterpret_cast<uint2*>(w1t);   // row c at c*(RW/4) uint2
        for (int i = t - 64; i < (KS / 4) * 8; i += 192) {  // 384 iters, 2 each
            const int kq4 = i >> 3, cq = i & 7;
            const int k0 = kq4 * 4;
            const float4 a = *reinterpret_cast<const float4*>(&W1s[(size_t)(k0 + 0) * H + cq * 4]);
            const float4 b = *reinterpret_cast<const float4*>(&W1s[(size_t)(k0 + 1) * H + cq * 4]);
            const float4 c = *reinterpret_cast<const float4*>(&W1s[(size_t)(k0 + 2) * H + cq * 4]);
            const float4 d = *reinterpret_cast<const float4*>(&W1s[(size_t)(k0 + 3) * H + cq * 4]);
            uint2 o;
            o.x = f2bf(a.x) | (f2bf(b.x) << 16);
            o.y = f2bf(c.x) | (f2bf(d.x) << 16);
            w1v[(cq * 4 + 0) * (RW / 4) + kq4] = o;
            o.x = f2bf(a.y) | (f2bf(b.y) << 16);
            o.y = f2bf(c.y) | (f2bf(d.y) << 16);
            w1v[(cq * 4 + 1) * (RW / 4) + kq4] = o;
            o.x = f2bf(a.z) | (f2bf(b.z) << 16);
            o.y = f2bf(c.z) | (f2bf(d.z) << 16);
            w1v[(cq * 4 + 2) * (RW / 4) + kq4] = o;
            o.x = f2bf(a.w) | (f2bf(b.w) << 16);
            o.y = f2bf(c.w) | (f2bf(d.w) << 16);
            w1v[(cq * 4 + 3) * (RW / 4) + kq4] = o;
        }
    }
    __syncthreads();
    const int n = n_sh;
    if (n == 0) return;                 // uniform exit

    const int cg = l & 15, gq = l >> 4;
    const int ct = w & 1;               // col-tile within 32-col slice
    const int sh = w >> 1;              // sample-half (0: s 0..31, 1: s 32..63)
    const short* wa = &w1t[(ct * 16 + cg) * RW + 8 * gq];
    const int gcol = hs * 32 + ct * 16 + cg;
    const float b1v = (dk == 0) ? b1[(size_t)aid * H + gcol] : 0.f;
    // interleaved part: thread-constant base for its column
    const int pbase = ((gcol >> 3) * DKN + dk) * 8 + (gcol & 7);

    for (int ch = 0; ch * S < n; ++ch) {
        // stage X chunk [64][192] as bf16: 8 floats/iter -> b128 LDS write
        for (int i = t; i < S * (KS / 8); i += 256) {       // 1536 iters, 6 each
            const int r = i / (KS / 8), q8 = i - r * (KS / 8);
            const float* xp = &X[(size_t)sidx[ch * S + r] * D + dk * KS + q8 * 8];
            const float4 v0 = *reinterpret_cast<const float4*>(xp);
            const float4 v1 = *reinterpret_cast<const float4*>(xp + 4);
            uint4 o;
            o.x = f2bf(v0.x) | (f2bf(v0.y) << 16);
            o.y = f2bf(v0.z) | (f2bf(v0.w) << 16);
            o.z = f2bf(v1.x) | (f2bf(v1.y) << 16);
            o.w = f2bf(v1.z) | (f2bf(v1.w) << 16);
            *reinterpret_cast<uint4*>(&xl[r * RW + q8 * 8]) = o;
        }
        __syncthreads();

        // 32 samples x 16 cols x 192k per wave: 12 MFMA, 6 B + 12 A ds_reads
        f32x4 acc0 = {0,0,0,0}, acc1 = {0,0,0,0};
        #pragma unroll
        for (int ks = 0; ks < KS / 32; ++ks) {
            const short8v bv = *reinterpret_cast<const short8v*>(wa + ks * 32);
            const int kof = ks * 32 + 8 * gq;
            acc0 = __builtin_amdgcn_mfma_f32_16x16x32_bf16(
                *reinterpret_cast<const short8v*>(&xl[(sh * 32 + cg)      * RW + kof]), bv, acc0, 0, 0, 0);
            acc1 = __builtin_amdgcn_mfma_f32_16x16x32_bf16(
                *reinterpret_cast<const short8v*>(&xl[(sh * 32 + 16 + cg) * RW + kof]), bv, acc1, 0, 0, 0);
        }

        // D[row=4gq+r][col=cg]; write bf16 partials (guarded: cv)
        const int cv = min(S, n - ch * S);
        #pragma unroll
        for (int r = 0; r < 4; ++r) {
            const int s0 = sh * 32 + gq * 4 + r;
            if (s0 < cv)
                part[(size_t)sidx[ch * S + s0] * (DKN * H) + pbase] =
                    (unsigned short)f2bf(acc0[r] + b1v);
            const int s1 = sh * 32 + 16 + gq * 4 + r;
            if (s1 < cv)
                part[(size_t)sidx[ch * S + s1] * (DKN * H) + pbase] =
                    (unsigned short)f2bf(acc1[r] + b1v);
        }
        if ((ch + 1) * S < n) __syncthreads();   // only when another chunk follows
    }
}

__global__ __launch_bounds__(256) void finish_kernel(
    const int*            __restrict__ aids,
    const unsigned short* __restrict__ part,
    const float*          __restrict__ W2,
    const float*          __restrict__ b2,
    float*                __restrict__ out)
{
    const int w = threadIdx.x >> 6, l = threadIdx.x & 63;
    const int half = l >> 5;                 // 0/1: two samples per wave
    const int m = l & 31;                    // col-octet 0..31
    const int s = blockIdx.x * 8 + w * 2 + half;
    const int aid = aids[s];

    // 4 dk-fragments for cols m*8..m*8+7: 4 CONTIGUOUS uint4 (64B, one line)
    const unsigned short* ps = part + ((size_t)s * 32 + m) * (DKN * 8);
    float v[8] = {0, 0, 0, 0, 0, 0, 0, 0};
    #pragma unroll
    for (int dk = 0; dk < DKN; ++dk) {
        const uint4 r = *reinterpret_cast<const uint4*>(ps + dk * 8);
        v[0] += bflo(r.x); v[1] += bfhi(r.x);
        v[2] += bflo(r.y); v[3] += bfhi(r.y);
        v[4] += bflo(r.z); v[5] += bfhi(r.z);
        v[6] += bflo(r.w); v[7] += bfhi(r.w);
    }

    // ReLU + layer-2 dot over these 8 cols
    const float4* W2v = reinterpret_cast<const float4*>(&W2[((size_t)aid * H + m * 8) * 2]);
    float p0 = 0.f, p1 = 0.f;
    #pragma unroll
    for (int c4 = 0; c4 < 4; ++c4) {
        const float4 wv = W2v[c4];           // cols 2c4 (x,y), 2c4+1 (z,w)
        const float o0 = fmaxf(v[c4 * 2 + 0], 0.f);
        const float o1 = fmaxf(v[c4 * 2 + 1], 0.f);
        p0 += o0 * wv.x + o1 * wv.z;
        p1 += o0 * wv.y + o1 * wv.w;
    }

    // reduce across the 32 lanes of this half-wave
    #pragma unroll
    for (int msk = 1; msk < 32; msk <<= 1) {
        p0 += __shfl_xor(p0, msk, 64);
        p1 += __shfl_xor(p1, msk, 64);
    }
    if (m == 0) {
        const float2 b2v = reinterpret_cast<const float2*>(b2)[aid];
        reinterpret_cast<float2*>(out)[s] = make_float2(p0 + b2v.x, p1 + b2v.y);
    }
}

// ---------------- fallback (round-1 monolithic kernel) ----------------
__global__ __launch_bounds__(256, 4) void aspect_mlp_fallback(
    const float* __restrict__ X, const int* __restrict__ aspect_ids,
    const float* __restrict__ W1_embs, const float* __restrict__ b1_embs,
    const float* __restrict__ W2_embs, const float* __restrict__ b2_embs,
    float* __restrict__ out)
{
    __shared__ float xs[D];
    __shared__ float pl[4][H];
    __shared__ float red[4][2];
    const int b = blockIdx.x, t = threadIdx.x, w = t >> 6, l = t & 63;
    const int aid = aspect_ids[b];
    const float4* Xr = reinterpret_cast<const float4*>(X + (size_t)b * D);
    if (t < D / 4) reinterpret_cast<float4*>(xs)[t] = Xr[t];
    __syncthreads();
    const float4* W1v = reinterpret_cast<const float4*>(W1_embs + (size_t)aid * (D * H));
    float4 acc = make_float4(0.f, 0.f, 0.f, 0.f);
    const int d0 = w * (D / 4);
    for (int d = d0; d < d0 + D / 4; ++d) {
        const float xv = xs[d];
        const float4 wv = W1v[d * (H / 4) + l];
        acc.x = fmaf(xv, wv.x, acc.x); acc.y = fmaf(xv, wv.y, acc.y);
        acc.z = fmaf(xv, wv.z, acc.z); acc.w = fmaf(xv, wv.w, acc.w);
    }
    reinterpret_cast<float4*>(pl[w])[l] = acc;
    __syncthreads();
    const float o = fmaxf(pl[0][t] + pl[1][t] + pl[2][t] + pl[3][t] + b1_embs[aid * H + t], 0.f);
    const float2 w2 = reinterpret_cast<const float2*>(W2_embs)[aid * H + t];
    float p0 = o * w2.x, p1 = o * w2.y;
    for (int s = 32; s; s >>= 1) { p0 += __shfl_xor(p0, s, 64); p1 += __shfl_xor(p1, s, 64); }
    if (l == 0) { red[w][0] = p0; red[w][1] = p1; }
    __syncthreads();
    if (t == 0) {
        const float2 bias2 = reinterpret_cast<const float2*>(b2_embs)[aid];
        out[b * 2 + 0] = red[0][0] + red[1][0] + red[2][0] + red[3][0] + bias2.x;
        out[b * 2 + 1] = red[0][1] + red[1][1] + red[2][1] + red[3][1] + bias2.y;
    }
}

extern "C" void kernel_launch(void* const* d_in, const int* in_sizes, int n_in,
                              void* d_out, int out_size, void* d_ws, size_t ws_size,
                              hipStream_t stream) {
    const float* X          = (const float*)d_in[0];
    const int*   aspect_ids = (const int*)d_in[1];
    const float* W1_embs    = (const float*)d_in[2];
    const float* b1_embs    = (const float*)d_in[3];
    const float* W2_embs    = (const float*)d_in[4];
    const float* b2_embs    = (const float*)d_in[5];
    float*       out        = (float*)d_out;

    const int Brt = in_sizes[0] / D;
    const int na  = in_sizes[2] / (D * H);

    if (Brt != NB || na != NA || ws_size < WS_NEEDED) {
        aspect_mlp_fallback<<<Brt, 256, 0, stream>>>(
            X, aspect_ids, W1_embs, b1_embs, W2_embs, b2_embs, out);
        return;
    }

    unsigned short* part = (unsigned short*)d_ws;

    gemm1_kernel<<<NA * HSN * DKN, 256, 0, stream>>>(
        X, aspect_ids, W1_embs, b1_embs, part);
    finish_kernel<<<NB / 8, 256, 0, stream>>>(
        aspect_ids, part, W2_embs, b2_embs, out);
}

// Round 19
// 13.870 us; speedup vs baseline: 1.0186x; 1.0186x over previous
//
#include <hip/hip_runtime.h>

// MFMA aspect-grouped 2-layer MLP, 2 dispatches, in-LDS transpose.
// == Round-17 configuration (best measured: 13.77 us) ==
//   gemm1:  flat 640-block grid: hs=bid/80 (0..7, 32-col slice), p=bid%80,
//           aid=p%20, dk=p/20 (0..3, 192-k slice). hs stride 80 = 0 mod 8 ->
//           the 8 hs-blocks sharing one (aid,dk) X-slice sit on one XCD.
//           Wave 0 ballot-scans aspect_ids (int4, deterministic, identical in
//           every block) -> sidx (padded to x64) while waves 1-3 transpose
//           W1 tile [192k][32c] fp32 -> bf16 W1T_lds [32c][192k] via 4k x 4c
//           subtiles (uint2 writes); one barrier. One X stage [64][192] bf16
//           at b128 (8 floats/iter). Wave role: ct=w&1 col-tile, sh=w>>1
//           sample-half: 32 samples x 16 cols x 192k = 12 MFMA (6 B + 12 A
//           ds_read_b128). bf16 part[sample][dk][col] (+b1 at dk==0).
//   finish: 128 blocks; 2 samples/wave (32 lanes x 8 cols), uint4 part reads
//           (4 dk-partials), ReLU, x W2 + b2 -> out.

constexpr int D  = 768;
constexpr int H  = 256;
constexpr int NA = 20;
constexpr int NB = 1024;
constexpr int S  = 64;            // samples per chunk (aspects avg ~51 -> 1 chunk)
constexpr int DKN = 4;            // d-slices
constexpr int KS  = D / DKN;      // 192 k per block
constexpr int HSN = 8;            // 32-col slices
constexpr int RW  = KS + 8;       // 200 shorts/row (400B, 16B-aligned)

constexpr size_t WS_NEEDED = (size_t)NB * DKN * H * 2;   // bf16 part: 2 MB

typedef __attribute__((ext_vector_type(8))) short short8v;  // 8 bf16
typedef __attribute__((ext_vector_type(4))) float f32x4;

__device__ __forceinline__ unsigned f2bf(float x) {   // RTN-even, low 16
    const unsigned u = __float_as_uint(x);
    return (u + 0x7FFFu + ((u >> 16) & 1u)) >> 16;
}
__device__ __forceinline__ float bflo(unsigned u) { return __uint_as_float(u << 16); }
__device__ __forceinline__ float bfhi(unsigned u) { return __uint_as_float(u & 0xFFFF0000u); }

__global__ __launch_bounds__(256, 3) void gemm1_kernel(
    const float* __restrict__ X,
    const int*   __restrict__ aids,
    const float* __restrict__ W1,
    const float* __restrict__ b1,
    unsigned short* __restrict__ part)   // bf16 [NB][DKN][H]
{
    __shared__ __align__(16) short w1t[32 * RW];   // bf16 W1T [32c][192k]
    __shared__ __align__(16) short xl[S * RW];     // bf16 X   [64s][192k]
    __shared__ int sidx[NB + S];
    __shared__ int n_sh;

    const int t = threadIdx.x;
    const int w = t >> 6, l = t & 63;
    const int bid = blockIdx.x;
    const int hs  = bid / 80;          // 0..7, 32-col slice
    const int p   = bid - hs * 80;     // 0..79
    const int aid = p % NA;            // 0..19
    const int dk  = p / NA;            // 0..3, 192-k slice

    if (w == 0) {
        // wave 0: ballot-scan, int4 loads; deterministic interleaved order,
        // identical in every block.
        int run = 0;
        #pragma unroll
        for (int base = 0; base < NB; base += 256) {
            const int4 v = *reinterpret_cast<const int4*>(&aids[base + l * 4]);
            #pragma unroll
            for (int j = 0; j < 4; ++j) {
                const int id = (j == 0) ? v.x : (j == 1) ? v.y : (j == 2) ? v.z : v.w;
                const unsigned long long m = __ballot(id == aid);
                const int pre = run + __popcll(m & ((1ull << l) - 1));
                if (id == aid) sidx[pre] = base + l * 4 + j;
                run += __popcll(m);
            }
        }
        if (run > 0) {
            const int last = sidx[run - 1];          // own-wave write, ordered
            const int npad = ((run + S - 1) / S) * S;
            if (run + l < npad) sidx[run + l] = last;
        }
        if (l == 0) n_sh = run;
    } else {
        // waves 1-3: W1 tile [192k][32c] -> bf16 W1T_lds [32c][192k].
        // i -> (k-quad kq4 0..47, col-quad cq 0..7): 4 f4 loads (rows
        // 4kq4..+3, cols cq*4..+3), pack 4 k per col -> uint2 write.
        const float* W1s = W1 + (size_t)aid * D * H + (size_t)dk * KS * H + hs * 32;
        uint2* w1v = reinterpret_cast<uint2*>(w1t);   // row c at c*(RW/4) uint2
        for (int i = t - 64; i < (KS / 4) * 8; i += 192) {  // 384 iters, 2 each
            const int kq4 = i >> 3, cq = i & 7;
            const int k0 = kq4 * 4;
            const float4 a = *reinterpret_cast<const float4*>(&W1s[(size_t)(k0 + 0) * H + cq * 4]);
            const float4 b = *reinterpret_cast<const float4*>(&W1s[(size_t)(k0 + 1) * H + cq * 4]);
            const float4 c = *reinterpret_cast<const float4*>(&W1s[(size_t)(k0 + 2) * H + cq * 4]);
            const float4 d = *reinterpret_cast<const float4*>(&W1s[(size_t)(k0 + 3) * H + cq * 4]);
            uint2 o;
            o.x = f2bf(a.x) | (f2bf(b.x) << 16);
            o.y = f2bf(c.x) | (f2bf(d.x) << 16);
            w1v[(cq * 4 + 0) * (RW / 4) + kq4] = o;
            o.x = f2bf(a.y) | (f2bf(b.y) << 16);
            o.y = f2bf(c.y) | (f2bf(d.y) << 16);
            w1v[(cq * 4 + 1) * (RW / 4) + kq4] = o;
            o.x = f2bf(a.z) | (f2bf(b.z) << 16);
            o.y = f2bf(c.z) | (f2bf(d.z) << 16);
            w1v[(cq * 4 + 2) * (RW / 4) + kq4] = o;
            o.x = f2bf(a.w) | (f2bf(b.w) << 16);
            o.y = f2bf(c.w) | (f2bf(d.w) << 16);
            w1v[(cq * 4 + 3) * (RW / 4) + kq4] = o;
        }
    }
    __syncthreads();
    const int n = n_sh;
    if (n == 0) return;                 // uniform exit

    const int cg = l & 15, gq = l >> 4;
    const int ct = w & 1;               // col-tile within 32-col slice
    const int sh = w >> 1;              // sample-half (0: s 0..31, 1: s 32..63)
    const short* wa = &w1t[(ct * 16 + cg) * RW + 8 * gq];
    const int gcol = hs * 32 + ct * 16 + cg;
    const float b1v = (dk == 0) ? b1[(size_t)aid * H + gcol] : 0.f;

    for (int ch = 0; ch * S < n; ++ch) {
        // stage X chunk [64][192] as bf16: 8 floats/iter -> b128 LDS write
        for (int i = t; i < S * (KS / 8); i += 256) {       // 1536 iters, 6 each
            const int r = i / (KS / 8), q8 = i - r * (KS / 8);
            const float* xp = &X[(size_t)sidx[ch * S + r] * D + dk * KS + q8 * 8];
            const float4 v0 = *reinterpret_cast<const float4*>(xp);
            const float4 v1 = *reinterpret_cast<const float4*>(xp + 4);
            uint4 o;
            o.x = f2bf(v0.x) | (f2bf(v0.y) << 16);
            o.y = f2bf(v0.z) | (f2bf(v0.w) << 16);
            o.z = f2bf(v1.x) | (f2bf(v1.y) << 16);
            o.w = f2bf(v1.z) | (f2bf(v1.w) << 16);
            *reinterpret_cast<uint4*>(&xl[r * RW + q8 * 8]) = o;
        }
        __syncthreads();

        // 32 samples x 16 cols x 192k per wave: 12 MFMA, 6 B + 12 A ds_reads
        f32x4 acc0 = {0,0,0,0}, acc1 = {0,0,0,0};
        #pragma unroll
        for (int ks = 0; ks < KS / 32; ++ks) {
            const short8v bv = *reinterpret_cast<const short8v*>(wa + ks * 32);
            const int kof = ks * 32 + 8 * gq;
            acc0 = __builtin_amdgcn_mfma_f32_16x16x32_bf16(
                *reinterpret_cast<const short8v*>(&xl[(sh * 32 + cg)      * RW + kof]), bv, acc0, 0, 0, 0);
            acc1 = __builtin_amdgcn_mfma_f32_16x16x32_bf16(
                *reinterpret_cast<const short8v*>(&xl[(sh * 32 + 16 + cg) * RW + kof]), bv, acc1, 0, 0, 0);
        }

        // D[row=4gq+r][col=cg]; write bf16 partials (guarded: cv)
        const int cv = min(S, n - ch * S);
        #pragma unroll
        for (int r = 0; r < 4; ++r) {
            const int s0 = sh * 32 + gq * 4 + r;
            if (s0 < cv)
                part[((size_t)sidx[ch * S + s0] * DKN + dk) * H + gcol] =
                    (unsigned short)f2bf(acc0[r] + b1v);
            const int s1 = sh * 32 + 16 + gq * 4 + r;
            if (s1 < cv)
                part[((size_t)sidx[ch * S + s1] * DKN + dk) * H + gcol] =
                    (unsigned short)f2bf(acc1[r] + b1v);
        }
        if ((ch + 1) * S < n) __syncthreads();   // only when another chunk follows
    }
}

__global__ __launch_bounds__(256) void finish_kernel(
    const int*            __restrict__ aids,
    const unsigned short* __restrict__ part,
    const float*          __restrict__ W2,
    const float*          __restrict__ b2,
    float*                __restrict__ out)
{
    const int w = threadIdx.x >> 6, l = threadIdx.x & 63;
    const int half = l >> 5;                 // 0/1: two samples per wave
    const int m = l & 31;                    // col-octet 0..31
    const int s = blockIdx.x * 8 + w * 2 + half;
    const int aid = aids[s];

    // accumulate 8 cols (m*8 .. m*8+7) over 4 dk-partials, uint4 loads
    const unsigned short* ps = part + (size_t)s * DKN * H + m * 8;
    float v[8] = {0, 0, 0, 0, 0, 0, 0, 0};
    #pragma unroll
    for (int dk = 0; dk < DKN; ++dk) {
        const uint4 r = *reinterpret_cast<const uint4*>(ps + dk * H);
        v[0] += bflo(r.x); v[1] += bfhi(r.x);
        v[2] += bflo(r.y); v[3] += bfhi(r.y);
        v[4] += bflo(r.z); v[5] += bfhi(r.z);
        v[6] += bflo(r.w); v[7] += bfhi(r.w);
    }

    // ReLU + layer-2 dot over these 8 cols
    const float4* W2v = reinterpret_cast<const float4*>(&W2[((size_t)aid * H + m * 8) * 2]);
    float p0 = 0.f, p1 = 0.f;
    #pragma unroll
    for (int c4 = 0; c4 < 4; ++c4) {
        const float4 wv = W2v[c4];           // cols 2c4 (x,y), 2c4+1 (z,w)
        const float o0 = fmaxf(v[c4 * 2 + 0], 0.f);
        const float o1 = fmaxf(v[c4 * 2 + 1], 0.f);
        p0 += o0 * wv.x + o1 * wv.z;
        p1 += o0 * wv.y + o1 * wv.w;
    }

    // reduce across the 32 lanes of this half-wave
    #pragma unroll
    for (int msk = 1; msk < 32; msk <<= 1) {
        p0 += __shfl_xor(p0, msk, 64);
        p1 += __shfl_xor(p1, msk, 64);
    }
    if (m == 0) {
        const float2 b2v = reinterpret_cast<const float2*>(b2)[aid];
        reinterpret_cast<float2*>(out)[s] = make_float2(p0 + b2v.x, p1 + b2v.y);
    }
}

// ---------------- fallback (round-1 monolithic kernel) ----------------
__global__ __launch_bounds__(256, 4) void aspect_mlp_fallback(
    const float* __restrict__ X, const int* __restrict__ aspect_ids,
    const float* __restrict__ W1_embs, const float* __restrict__ b1_embs,
    const float* __restrict__ W2_embs, const float* __restrict__ b2_embs,
    float* __restrict__ out)
{
    __shared__ float xs[D];
    __shared__ float pl[4][H];
    __shared__ float red[4][2];
    const int b = blockIdx.x, t = threadIdx.x, w = t >> 6, l = t & 63;
    const int aid = aspect_ids[b];
    const float4* Xr = reinterpret_cast<const float4*>(X + (size_t)b * D);
    if (t < D / 4) reinterpret_cast<float4*>(xs)[t] = Xr[t];
    __syncthreads();
    const float4* W1v = reinterpret_cast<const float4*>(W1_embs + (size_t)aid * (D * H));
    float4 acc = make_float4(0.f, 0.f, 0.f, 0.f);
    const int d0 = w * (D / 4);
    for (int d = d0; d < d0 + D / 4; ++d) {
        const float xv = xs[d];
        const float4 wv = W1v[d * (H / 4) + l];
        acc.x = fmaf(xv, wv.x, acc.x); acc.y = fmaf(xv, wv.y, acc.y);
        acc.z = fmaf(xv, wv.z, acc.z); acc.w = fmaf(xv, wv.w, acc.w);
    }
    reinterpret_cast<float4*>(pl[w])[l] = acc;
    __syncthreads();
    const float o = fmaxf(pl[0][t] + pl[1][t] + pl[2][t] + pl[3][t] + b1_embs[aid * H + t], 0.f);
    const float2 w2 = reinterpret_cast<const float2*>(W2_embs)[aid * H + t];
    float p0 = o * w2.x, p1 = o * w2.y;
    for (int s = 32; s; s >>= 1) { p0 += __shfl_xor(p0, s, 64); p1 += __shfl_xor(p1, s, 64); }
    if (l == 0) { red[w][0] = p0; red[w][1] = p1; }
    __syncthreads();
    if (t == 0) {
        const float2 bias2 = reinterpret_cast<const float2*>(b2_embs)[aid];
        out[b * 2 + 0] = red[0][0] + red[1][0] + red[2][0] + red[3][0] + bias2.x;
        out[b * 2 + 1] = red[0][1] + red[1][1] + red[2][1] + red[3][1] + bias2.y;
    }
}

extern "C" void kernel_launch(void* const* d_in, const int* in_sizes, int n_in,
                              void* d_out, int out_size, void* d_ws, size_t ws_size,
                              hipStream_t stream) {
    const float* X          = (const float*)d_in[0];
    const int*   aspect_ids = (const int*)d_in[1];
    const float* W1_embs    = (const float*)d_in[2];
    const float* b1_embs    = (const float*)d_in[3];
    const float* W2_embs    = (const float*)d_in[4];
    const float* b2_embs    = (const float*)d_in[5];
    float*       out        = (float*)d_out;

    const int Brt = in_sizes[0] / D;
    const int na  = in_sizes[2] / (D * H);

    if (Brt != NB || na != NA || ws_size < WS_NEEDED) {
        aspect_mlp_fallback<<<Brt, 256, 0, stream>>>(
            X, aspect_ids, W1_embs, b1_embs, W2_embs, b2_embs, out);
        return;
    }

    unsigned short* part = (unsigned short*)d_ws;

    gemm1_kernel<<<NA * HSN * DKN, 256, 0, stream>>>(
        X, aspect_ids, W1_embs, b1_embs, part);
    finish_kernel<<<NB / 8, 256, 0, stream>>>(
        aspect_ids, part, W2_embs, b2_embs, out);
}